// Round 1
// baseline (213.908 us; speedup 1.0000x reference)
//
#include <hip/hip_runtime.h>

// YOLO loss, forward only. pred/target: (16384, 7, 7, 30) fp32, out: scalar fp32.
// S=7, B=2, CLS=20, N=30, LAMBDA_COORD=5, LAMBDA_NOOBJ=0.5, BATCH=16384.
// NOTE: reference conf_loc = arange(B)*B+4 = [4,6] (not [4,9]) — mirrored here.

#define TPB 256
#define CELLS 256            // cells per block tile (== TPB, one cell/thread)
#define NPER 30              // floats per cell
#define NFLOAT (CELLS * NPER)  // 7680 floats per array per tile
#define R_TOTAL (16384 * 7 * 7) // 802816 cells
#define NBLOCKS (R_TOTAL / CELLS) // 3136

__global__ __launch_bounds__(TPB, 2) void yolo_loss_kernel(
    const float* __restrict__ pred, const float* __restrict__ target,
    float* __restrict__ out)
{
    __shared__ float sp[NFLOAT];
    __shared__ float st[NFLOAT];
    __shared__ float red[TPB / 64];

    const int tid = threadIdx.x;
    const size_t base = (size_t)blockIdx.x * NFLOAT;
    const float* gp = pred + base;
    const float* gt = target + base;

    // Coalesced float4 staging: 7680 floats = 1920 float4 across 256 threads.
    for (int f = tid * 4; f < NFLOAT; f += TPB * 4) {
        float4 vp = *(const float4*)(gp + f);
        float4 vt = *(const float4*)(gt + f);
        *(float4*)(&sp[f]) = vp;
        *(float4*)(&st[f]) = vt;
    }
    __syncthreads();

    const float* p = &sp[tid * NPER];
    const float* t = &st[tid * NPER];

    float sum = 0.0f;
    const float t4 = t[4];
    if (t4 == 0.0f) {
        // noobj: 0.5 * sum over conf_loc=[4,6] of (p-t)^2
        float d4 = p[4] - t[4];
        float d6 = p[6] - t[6];
        sum = 0.5f * (d4 * d4 + d6 * d6);
    } else if (t4 == 1.0f) {
        // target box -> xyxy
        float tx1 = t[0] - t[2] * 0.5f, ty1 = t[1] - t[3] * 0.5f;
        float tx2 = t[0] + t[2] * 0.5f, ty2 = t[1] + t[3] * 0.5f;
        float area2 = (tx2 - tx1) * (ty2 - ty1);
        float iou0, iou1;
        #pragma unroll
        for (int b = 0; b < 2; b++) {
            const float* pb = p + b * 5;
            float x1 = pb[0] - pb[2] * 0.5f, y1 = pb[1] - pb[3] * 0.5f;
            float x2 = pb[0] + pb[2] * 0.5f, y2 = pb[1] + pb[3] * 0.5f;
            float ltx = fmaxf(x1, tx1), lty = fmaxf(y1, ty1);
            float rbx = fminf(x2, tx2), rby = fminf(y2, ty2);
            float w = fmaxf(rbx - ltx, 0.0f), h = fmaxf(rby - lty, 0.0f);
            float inter = w * h;
            float area1 = (x2 - x1) * (y2 - y1);
            float uni = area1 + area2 - inter;
            float iou = (uni > 0.0f) ? (inter / uni) : 0.0f;
            if (b == 0) iou0 = iou; else iou1 = iou;
        }
        // argmax over 2 -> first max index on ties
        int j = (iou1 > iou0) ? 1 : 0;
        float max_iou = fmaxf(iou0, iou1);
        const float* resp = p + j * 5;
        float dx = resp[0] - t[0];
        float dy = resp[1] - t[1];
        float sw = sqrtf(fmaxf(resp[2], 0.0f)) - sqrtf(fmaxf(t[2], 0.0f));
        float sh = sqrtf(fmaxf(resp[3], 0.0f)) - sqrtf(fmaxf(t[3], 0.0f));
        float coord = dx * dx + dy * dy + sw * sw + sh * sh;
        float dc = resp[4] - max_iou;
        float cls = 0.0f;
        #pragma unroll
        for (int k = 10; k < 30; k++) {
            float d = p[k] - t[k];
            cls += d * d;
        }
        sum = 5.0f * coord + dc * dc + cls;
    }
    // (t4 guaranteed in {0,1} by setup; any other value contributes 0, matching ref)

    // wave-64 reduction
    #pragma unroll
    for (int off = 32; off > 0; off >>= 1)
        sum += __shfl_down(sum, off, 64);
    if ((tid & 63) == 0) red[tid >> 6] = sum;
    __syncthreads();
    if (tid == 0) {
        float s = red[0] + red[1] + red[2] + red[3];
        atomicAdd(out, s * (1.0f / 16384.0f));
    }
}

extern "C" void kernel_launch(void* const* d_in, const int* in_sizes, int n_in,
                              void* d_out, int out_size, void* d_ws, size_t ws_size,
                              hipStream_t stream) {
    const float* pred = (const float*)d_in[0];
    const float* target = (const float*)d_in[1];
    float* out = (float*)d_out;
    // d_out is poisoned with 0xAA before every launch; we accumulate into it.
    hipMemsetAsync(out, 0, sizeof(float), stream);
    yolo_loss_kernel<<<NBLOCKS, TPB, 0, stream>>>(pred, target, out);
}

// Round 2
// 211.408 us; speedup vs baseline: 1.0118x; 1.0118x over previous
//
#include <hip/hip_runtime.h>

// YOLO loss, forward only. pred/target: (16384, 7, 7, 30) fp32, out: scalar fp32.
// S=7, B=2, CLS=20, N=30, LAMBDA_COORD=5, LAMBDA_NOOBJ=0.5, BATCH=16384.
// NOTE: reference conf_loc = arange(B)*B+4 = [4,6] (not [4,9]) — mirrored here.
//
// R1: register-direct version. No LDS staging (zero reuse -> staging was pure
// overhead; 60.5 KB LDS capped occupancy at 2 blocks/CU = 17%, latency-bound
// at 78 us). Each thread loads its own cell via 15+15 independent float2
// loads (cell = 120 B, 8 B-aligned). resp-box select done with cndmask
// ternaries, never dynamic-indexing the register array.

#define TPB 256
#define NPER 30
#define R_TOTAL (16384 * 7 * 7)    // 802816 cells
#define NBLOCKS (R_TOTAL / TPB)    // 3136

__global__ __launch_bounds__(TPB, 4) void yolo_loss_kernel(
    const float* __restrict__ pred, const float* __restrict__ target,
    float* __restrict__ out)
{
    __shared__ float red[TPB / 64];

    const int tid = threadIdx.x;
    const size_t cell = (size_t)blockIdx.x * TPB + tid;

    float p[NPER], t[NPER];
    {
        const float2* gp = (const float2*)(pred + cell * NPER);
        const float2* gt = (const float2*)(target + cell * NPER);
        #pragma unroll
        for (int i = 0; i < NPER / 2; i++) {
            float2 v = gp[i];
            p[2 * i] = v.x; p[2 * i + 1] = v.y;
        }
        #pragma unroll
        for (int i = 0; i < NPER / 2; i++) {
            float2 v = gt[i];
            t[2 * i] = v.x; t[2 * i + 1] = v.y;
        }
    }

    float sum = 0.0f;
    const float t4 = t[4];
    if (t4 == 0.0f) {
        // noobj: 0.5 * sum over conf_loc=[4,6] of (p-t)^2
        float d4 = p[4] - t[4];
        float d6 = p[6] - t[6];
        sum = 0.5f * (d4 * d4 + d6 * d6);
    } else if (t4 == 1.0f) {
        // target box -> xyxy (mirror reference float op order)
        float tx1 = t[0] - t[2] * 0.5f, ty1 = t[1] - t[3] * 0.5f;
        float tx2 = t[0] + t[2] * 0.5f, ty2 = t[1] + t[3] * 0.5f;
        float area2 = (tx2 - tx1) * (ty2 - ty1);

        // box 0
        float ax1 = p[0] - p[2] * 0.5f, ay1 = p[1] - p[3] * 0.5f;
        float ax2 = p[0] + p[2] * 0.5f, ay2 = p[1] + p[3] * 0.5f;
        float w0 = fmaxf(fminf(ax2, tx2) - fmaxf(ax1, tx1), 0.0f);
        float h0 = fmaxf(fminf(ay2, ty2) - fmaxf(ay1, ty1), 0.0f);
        float inter0 = w0 * h0;
        float uni0 = (ax2 - ax1) * (ay2 - ay1) + area2 - inter0;
        float iou0 = (uni0 > 0.0f) ? (inter0 / uni0) : 0.0f;

        // box 1
        float bx1 = p[5] - p[7] * 0.5f, by1 = p[6] - p[8] * 0.5f;
        float bx2 = p[5] + p[7] * 0.5f, by2 = p[6] + p[8] * 0.5f;
        float w1 = fmaxf(fminf(bx2, tx2) - fmaxf(bx1, tx1), 0.0f);
        float h1 = fmaxf(fminf(by2, ty2) - fmaxf(by1, ty1), 0.0f);
        float inter1 = w1 * h1;
        float uni1 = (bx2 - bx1) * (by2 - by1) + area2 - inter1;
        float iou1 = (uni1 > 0.0f) ? (inter1 / uni1) : 0.0f;

        // argmax over 2 -> first max index on ties
        bool j1 = (iou1 > iou0);
        float max_iou = fmaxf(iou0, iou1);
        // responsible box via per-element select (no dynamic reg indexing)
        float r0 = j1 ? p[5] : p[0];
        float r1 = j1 ? p[6] : p[1];
        float r2 = j1 ? p[7] : p[2];
        float r3 = j1 ? p[8] : p[3];
        float r4 = j1 ? p[9] : p[4];

        float dx = r0 - t[0];
        float dy = r1 - t[1];
        float sw = sqrtf(fmaxf(r2, 0.0f)) - sqrtf(fmaxf(t[2], 0.0f));
        float sh = sqrtf(fmaxf(r3, 0.0f)) - sqrtf(fmaxf(t[3], 0.0f));
        float coord = dx * dx + dy * dy + sw * sw + sh * sh;
        float dc = r4 - max_iou;

        float cls = 0.0f;
        #pragma unroll
        for (int k = 10; k < NPER; k++) {
            float d = p[k] - t[k];
            cls += d * d;
        }
        sum = 5.0f * coord + dc * dc + cls;
    }
    // (t4 guaranteed in {0,1} by setup; any other value contributes 0, matching ref)

    // wave-64 butterfly-free reduction via shfl_down
    #pragma unroll
    for (int off = 32; off > 0; off >>= 1)
        sum += __shfl_down(sum, off, 64);
    if ((tid & 63) == 0) red[tid >> 6] = sum;
    __syncthreads();
    if (tid == 0) {
        float s = red[0] + red[1] + red[2] + red[3];
        atomicAdd(out, s * (1.0f / 16384.0f));
    }
}

extern "C" void kernel_launch(void* const* d_in, const int* in_sizes, int n_in,
                              void* d_out, int out_size, void* d_ws, size_t ws_size,
                              hipStream_t stream) {
    const float* pred = (const float*)d_in[0];
    const float* target = (const float*)d_in[1];
    float* out = (float*)d_out;
    // d_out is poisoned with 0xAA before every launch; we accumulate into it.
    hipMemsetAsync(out, 0, sizeof(float), stream);
    yolo_loss_kernel<<<NBLOCKS, TPB, 0, stream>>>(pred, target, out);
}